// Round 4
// baseline (484.708 us; speedup 1.0000x reference)
//
#include <hip/hip_runtime.h>
#include <math.h>

#define BATCH 128
#define NINS  4096
#define NHID  128
#define KH    64
#define NPART 128                   // 128 tiles of 32 n per batch
#define PART_STRIDE 136             // [0]=L, [8..135]=o[128]; 16B-aligned
#define O_OFF 8
#define TPW 2                       // tiles per wave
#define XP 136                      // WbT row pitch in ushort (128 bf16 + 8 pad)

typedef __attribute__((ext_vector_type(8))) short short8;   // 8 x bf16
typedef __attribute__((ext_vector_type(4))) float f32x4;
typedef __attribute__((ext_vector_type(4))) unsigned int u32x4;

__device__ inline unsigned short f2bf(float f) {
    union { float f; unsigned u; } v; v.f = f;
    return (unsigned short)((v.u + 0x7FFFu + ((v.u >> 16) & 1u)) >> 16);
}

// packed fp32x2 -> bf16x2 as u32 (hardware v_cvt_pk_bf16_f32 on gfx950)
__device__ inline unsigned cvt_pk_u32(float a, float b) {
#if __has_builtin(__builtin_amdgcn_cvt_pk_bf16_f32)
    typedef __attribute__((ext_vector_type(2))) __bf16 bf16x2;
    bf16x2 p = __builtin_amdgcn_cvt_pk_bf16_f32(a, b);
    unsigned u; __builtin_memcpy(&u, &p, 4); return u;
#else
    return (unsigned)f2bf(a) | ((unsigned)f2bf(b) << 16);
#endif
}

// --------------------------------------------------------------------------
// Kernel B: MFMA main pass, direct global->register A-fragments (compiler-
// scheduled loads). Fused c-compute (R3). No per-tile max subtraction (R3).
// R4: the weighted sum o[d] = sum_n e_n x[n][d] is computed FROM THE LIVE
// bf16 A-FRAGMENTS via a 4-round reduce-scatter butterfly over the 16-lane
// m16 group — the old global re-read of the 16 KB tile (fully L1-evicted by
// the other 15 resident waves, substantially L2-missed) is deleted, saving
// up to a second HBM fetch of the whole input. bf16 x in the o-sum adds
// ~3e-5 error (w is near-uniform), invisible vs the bf16-matmul's 0.003.
// --------------------------------------------------------------------------
__global__ __launch_bounds__(256, 4)
void att_partial(const float* __restrict__ inputs,
                 const int* __restrict__ index_p,
                 const float* __restrict__ W1,
                 const float* __restrict__ b1,
                 const float* __restrict__ W2,
                 const float* __restrict__ b2_p,
                 float* __restrict__ part) {
    __shared__ unsigned short WbT[KH][XP];       // [out k][hidden d] bf16, 17.4 KB
    __shared__ float csp[4][KH];                 // c partial sums (d-quarters)
    __shared__ float ebuf[4][32];

    const int tid  = threadIdx.x;
    const int lane = tid & 63;
    const int wv   = tid >> 6;
    const int b    = blockIdx.y;
    const int quad = lane >> 4;
    const int m16  = lane & 15;

    const float* xb = inputs + (size_t)b * NINS * NHID;

    // ---- stage WbT[k][d] = bf16(W1[128+d][k]) (whole block, once) ----
    {
        const int n  = tid >> 2;            // 0..63 (output k)
        const int kb = (tid & 3) * 32;      // 0,32,64,96 (hidden d base)
        const float* wp = W1 + (size_t)(NHID + kb) * KH + n;
        #pragma unroll
        for (int j = 0; j < 32; j += 2) {
            unsigned u = cvt_pk_u32(wp[(size_t)j * KH], wp[(size_t)(j + 1) * KH]);
            *(unsigned*)&WbT[n][kb + j] = u;
        }
    }

    // ---- fused c-compute: csp[q][k] = partial_d own[d]*W1[d][k] ----
    {
        const int kk = lane;                 // 0..63
        const int dq = wv;                   // d-quarter
        const int idx = index_p[0];
        const float* own = xb + (size_t)idx * NHID;
        float ca = (dq == 0) ? b1[kk] : 0.0f;
        #pragma unroll 8
        for (int d = dq * 32; d < dq * 32 + 32; ++d)
            ca = fmaf(own[d], W1[(size_t)d * KH + kk], ca);
        csp[dq][kk] = ca;
    }
    __syncthreads();

    float w2v[4];
    #pragma unroll
    for (int nf = 0; nf < 4; ++nf) w2v[nf] = W2[nf * 16 + m16];
    const float b2v = b2_p[0];
    float cv[4];
    #pragma unroll
    for (int nf = 0; nf < 4; ++nf) {
        const int kk = nf * 16 + m16;
        cv[nf] = (csp[0][kk] + csp[1][kk]) + (csp[2][kk] + csp[3][kk]);
    }

    const int base = (blockIdx.x * 4 + wv) * TPW;   // first tile of this wave

    #pragma unroll
    for (int t = 0; t < TPW; ++t) {
        const int tile = base + t;
        const int n0   = tile * 32;

        // ---- A-frags: global fp32 -> bf16 regs (no LDS round trip) ----
        short8 Af[2][4];    // [mf][ks]
        #pragma unroll
        for (int mf = 0; mf < 2; ++mf) {
            const float* rp = xb + (size_t)(n0 + mf * 16 + m16) * NHID + quad * 8;
            #pragma unroll
            for (int ks = 0; ks < 4; ++ks) {
                f32x4 v0 = *(const f32x4*)(rp + ks * 32);
                f32x4 v1 = *(const f32x4*)(rp + ks * 32 + 4);
                u32x4 u;
                u.x = cvt_pk_u32(v0.x, v0.y);
                u.y = cvt_pk_u32(v0.z, v0.w);
                u.z = cvt_pk_u32(v1.x, v1.y);
                u.w = cvt_pk_u32(v1.z, v1.w);
                __builtin_memcpy(&Af[mf][ks], &u, 16);
            }
        }

        f32x4 acc[2][4];
        #pragma unroll
        for (int mf = 0; mf < 2; ++mf)
            #pragma unroll
            for (int nf = 0; nf < 4; ++nf) {
                f32x4 z = {cv[nf], cv[nf], cv[nf], cv[nf]};
                acc[mf][nf] = z;
            }

        #pragma unroll
        for (int ks = 0; ks < 4; ++ks) {
            short8 Bf[4];
            #pragma unroll
            for (int nf = 0; nf < 4; ++nf)
                Bf[nf] = *(const short8*)&WbT[nf * 16 + m16][ks * 32 + quad * 8];
            #pragma unroll
            for (int mf = 0; mf < 2; ++mf)
                #pragma unroll
                for (int nf = 0; nf < 4; ++nf)
                    acc[mf][nf] = __builtin_amdgcn_mfma_f32_16x16x32_bf16(
                        Af[mf][ks], Bf[nf], acc[mf][nf], 0, 0, 0);
        }

        // ---- epilogue: att[n] = b2 + sum_k relu(h[n][k]) * W2[k] ----
        // C layout: row(n-in-tile) = mf*16 + quad*4 + r, col(hidden k) = nf*16+m16
        float att[2][4];
        #pragma unroll
        for (int mf = 0; mf < 2; ++mf)
            #pragma unroll
            for (int r = 0; r < 4; ++r) {
                float s = 0.0f;
                #pragma unroll
                for (int nf = 0; nf < 4; ++nf)
                    s = fmaf(fmaxf(acc[mf][nf][r], 0.0f), w2v[nf], s);
                s += __shfl_xor(s, 1);
                s += __shfl_xor(s, 2);
                s += __shfl_xor(s, 4);
                s += __shfl_xor(s, 8);
                att[mf][r] = s + b2v;
            }

        // ---- exp (no max subtraction) + L reduce ----
        float ev[2][4];
        float L = 0.0f;
        #pragma unroll
        for (int mf = 0; mf < 2; ++mf)
            #pragma unroll
            for (int r = 0; r < 4; ++r) {
                ev[mf][r] = __expf(att[mf][r]);
                L += ev[mf][r];
            }
        L += __shfl_xor(L, 16);
        L += __shfl_xor(L, 32);

        if (m16 == 0) {
            #pragma unroll
            for (int mf = 0; mf < 2; ++mf)
                #pragma unroll
                for (int r = 0; r < 4; ++r)
                    ebuf[wv][mf * 16 + quad * 4 + r] = ev[mf][r];
        }
        // same-wave DS ordering; compiler inserts lgkmcnt wait before reads

        // ---- weighted sum from LIVE A-frags (no global re-read) ----
        // lane (quad,m16) holds x[m16][d], x[m16+16][d] for
        // d = ks*32 + quad*8 + j  (slot i = ks*8 + j, 32 slots/lane)
        const float e0 = ebuf[wv][m16];
        const float e1 = ebuf[wv][m16 + 16];
        float po[32];
        #pragma unroll
        for (int ks = 0; ks < 4; ++ks) {
            u32x4 a0, a1;
            __builtin_memcpy(&a0, &Af[0][ks], 16);
            __builtin_memcpy(&a1, &Af[1][ks], 16);
            #pragma unroll
            for (int w = 0; w < 4; ++w) {
                const float x0l = __uint_as_float(a0[w] << 16);
                const float x0h = __uint_as_float(a0[w] & 0xffff0000u);
                const float x1l = __uint_as_float(a1[w] << 16);
                const float x1h = __uint_as_float(a1[w] & 0xffff0000u);
                po[ks * 8 + w * 2]     = fmaf(e0, x0l, e1 * x1l);
                po[ks * 8 + w * 2 + 1] = fmaf(e0, x0h, e1 * x1h);
            }
        }
        // reduce-scatter butterfly over the 16-lane m16 group: 4 rounds,
        // halving slots/lane; all indices compile-time (no scratch spill).
        // Round μ splits slot-bit (μ's position +1); lane keeps the half
        // matching its own m16 bit, sends the other.
        float p16[16];
        {
            const bool up = (m16 & 1);
            #pragma unroll
            for (int s = 0; s < 16; ++s) {
                const int i0 = ((s >> 1) << 2) | (s & 1);
                const int i1 = i0 | 2;
                const float send = up ? po[i0] : po[i1];
                const float recv = __shfl_xor(send, 1);
                p16[s] = (up ? po[i1] : po[i0]) + recv;
            }
        }
        float p8[8];
        {
            const bool up = (m16 & 2);
            #pragma unroll
            for (int s = 0; s < 8; ++s) {
                const int i0 = ((s >> 1) << 2) | (s & 1);
                const int i1 = i0 | 2;
                const float send = up ? p16[i0] : p16[i1];
                const float recv = __shfl_xor(send, 2);
                p8[s] = (up ? p16[i1] : p16[i0]) + recv;
            }
        }
        float p4[4];
        {
            const bool up = (m16 & 4);
            #pragma unroll
            for (int s = 0; s < 4; ++s) {
                const int i0 = ((s >> 1) << 2) | (s & 1);
                const int i1 = i0 | 2;
                const float send = up ? p8[i0] : p8[i1];
                const float recv = __shfl_xor(send, 4);
                p4[s] = (up ? p8[i1] : p8[i0]) + recv;
            }
        }
        float p2[2];
        {
            const bool up = (m16 & 8);
            #pragma unroll
            for (int s = 0; s < 2; ++s) {
                const int i0 = s;
                const int i1 = i0 | 2;
                const float send = up ? p4[i0] : p4[i1];
                const float recv = __shfl_xor(send, 8);
                p2[s] = (up ? p4[i1] : p4[i0]) + recv;
            }
        }
        // lane's final slots: i = 2*m16 + {0,1}  ->
        // d0 = (m16>>2)*32 + quad*8 + (m16&3)*2
        float* p = part + (size_t)(b * NPART + tile) * PART_STRIDE;
        if (lane == 0) p[0] = L;
        const int d0 = (m16 >> 2) * 32 + quad * 8 + (m16 & 3) * 2;
        float2 o2 = make_float2(p2[0], p2[1]);
        *(float2*)(p + O_OFF + d0) = o2;
    }
}

// --------------------------------------------------------------------------
// Kernel C: merge 128 partials per batch -> out[b][d]
// No max pass: S = sum of L_p (block reduce), then a coalesced plain sum
// over partials. No exp, single __syncthreads.
// --------------------------------------------------------------------------
__global__ void finalize(const float* __restrict__ part,
                         float* __restrict__ out) {
    __shared__ float wred[2];

    const int b = blockIdx.x;
    const int d = threadIdx.x;     // 0..127 (= partial index in phase 1)
    const float* pb = part + (size_t)b * NPART * PART_STRIDE;

    // phase 1: S = sum of per-partial L
    float s = pb[(size_t)d * PART_STRIDE];
    s += __shfl_xor(s, 1);
    s += __shfl_xor(s, 2);
    s += __shfl_xor(s, 4);
    s += __shfl_xor(s, 8);
    s += __shfl_xor(s, 16);
    s += __shfl_xor(s, 32);
    if ((d & 63) == 0) wred[d >> 6] = s;
    __syncthreads();
    const float S = wred[0] + wred[1];

    // phase 2: acc over partials, d is the hidden index (coalesced)
    float acc = 0.0f;
    #pragma unroll 8
    for (int p = 0; p < NPART; ++p)
        acc += pb[(size_t)p * PART_STRIDE + O_OFF + d];
    out[b * NHID + d] = acc / S;
}

// --------------------------------------------------------------------------
extern "C" void kernel_launch(void* const* d_in, const int* in_sizes, int n_in,
                              void* d_out, int out_size, void* d_ws, size_t ws_size,
                              hipStream_t stream) {
    const float* inputs = (const float*)d_in[0];
    const int*   index  = (const int*)  d_in[1];
    // d_in[2] = claims (unused by forward)
    const float* W1     = (const float*)d_in[3];
    const float* b1     = (const float*)d_in[4];
    const float* W2     = (const float*)d_in[5];
    const float* b2     = (const float*)d_in[6];
    float* out = (float*)d_out;

    float* part = (float*)d_ws;                 // 128*128*136 floats ~= 8.9 MB

    dim3 gB(NPART / (4 * TPW), BATCH);          // 16 x 128 = 2048 blocks, 4 waves
    att_partial<<<gB, dim3(256), 0, stream>>>(inputs, index, W1, b1, W2, b2, part);

    finalize<<<dim3(BATCH), dim3(NHID), 0, stream>>>(part, out);
}

// Round 5
// 407.920 us; speedup vs baseline: 1.1882x; 1.1882x over previous
//
#include <hip/hip_runtime.h>
#include <math.h>

#define BATCH 128
#define NINS  4096
#define NHID  128
#define KH    64
#define NPART 128                   // 128 tiles of 32 n per batch
#define PART_STRIDE 136             // [0]=L, [8..135]=o[128]; 16B-aligned
#define O_OFF 8
#define TPW 2                       // tiles per wave
#define XP 136                      // WbT row pitch in ushort (128 bf16 + 8 pad)

typedef __attribute__((ext_vector_type(8))) short short8;   // 8 x bf16
typedef __attribute__((ext_vector_type(4))) float f32x4;
typedef __attribute__((ext_vector_type(4))) unsigned int u32x4;

__device__ inline unsigned short f2bf(float f) {
    union { float f; unsigned u; } v; v.f = f;
    return (unsigned short)((v.u + 0x7FFFu + ((v.u >> 16) & 1u)) >> 16);
}

// packed fp32x2 -> bf16x2 as u32 (hardware v_cvt_pk_bf16_f32 on gfx950)
__device__ inline unsigned cvt_pk_u32(float a, float b) {
#if __has_builtin(__builtin_amdgcn_cvt_pk_bf16_f32)
    typedef __attribute__((ext_vector_type(2))) __bf16 bf16x2;
    bf16x2 p = __builtin_amdgcn_cvt_pk_bf16_f32(a, b);
    unsigned u; __builtin_memcpy(&u, &p, 4); return u;
#else
    return (unsigned)f2bf(a) | ((unsigned)f2bf(b) << 16);
#endif
}

// --------------------------------------------------------------------------
// Kernel B: MFMA main pass, direct global->register A-fragments (compiler-
// scheduled loads). Fused c-compute (R3). No per-tile max subtraction (R3).
// R5: o[d] = sum_n e_n x[n][d] computed FROM THE LIVE bf16 A-FRAGMENTS
// (input read from HBM exactly once — R4 confirmed FETCH 280 MB), with
// butterfly rounds 1-2 FUSED into the per-ks extraction so peak live state
// is ~30 floats, not 62 (R4 spilled: VGPR_Count 64, WRITE_SIZE 291 MB of
// scratch traffic, 217 us). Transients q[8]/r1[4] die each ks iteration;
// only p8[8] survives the loop.
// --------------------------------------------------------------------------
__global__ __launch_bounds__(256, 4)
void att_partial(const float* __restrict__ inputs,
                 const int* __restrict__ index_p,
                 const float* __restrict__ W1,
                 const float* __restrict__ b1,
                 const float* __restrict__ W2,
                 const float* __restrict__ b2_p,
                 float* __restrict__ part) {
    __shared__ unsigned short WbT[KH][XP];       // [out k][hidden d] bf16, 17.4 KB
    __shared__ float csp[4][KH];                 // c partial sums (d-quarters)
    __shared__ float ebuf[4][32];

    const int tid  = threadIdx.x;
    const int lane = tid & 63;
    const int wv   = tid >> 6;
    const int b    = blockIdx.y;
    const int quad = lane >> 4;
    const int m16  = lane & 15;

    const float* xb = inputs + (size_t)b * NINS * NHID;

    // ---- stage WbT[k][d] = bf16(W1[128+d][k]) (whole block, once) ----
    {
        const int n  = tid >> 2;            // 0..63 (output k)
        const int kb = (tid & 3) * 32;      // 0,32,64,96 (hidden d base)
        const float* wp = W1 + (size_t)(NHID + kb) * KH + n;
        #pragma unroll
        for (int j = 0; j < 32; j += 2) {
            unsigned u = cvt_pk_u32(wp[(size_t)j * KH], wp[(size_t)(j + 1) * KH]);
            *(unsigned*)&WbT[n][kb + j] = u;
        }
    }

    // ---- fused c-compute: csp[q][k] = partial_d own[d]*W1[d][k] ----
    {
        const int kk = lane;                 // 0..63
        const int dq = wv;                   // d-quarter
        const int idx = index_p[0];
        const float* own = xb + (size_t)idx * NHID;
        float ca = (dq == 0) ? b1[kk] : 0.0f;
        #pragma unroll 8
        for (int d = dq * 32; d < dq * 32 + 32; ++d)
            ca = fmaf(own[d], W1[(size_t)d * KH + kk], ca);
        csp[dq][kk] = ca;
    }
    __syncthreads();

    float w2v[4];
    #pragma unroll
    for (int nf = 0; nf < 4; ++nf) w2v[nf] = W2[nf * 16 + m16];
    const float b2v = b2_p[0];
    float cv[4];
    #pragma unroll
    for (int nf = 0; nf < 4; ++nf) {
        const int kk = nf * 16 + m16;
        cv[nf] = (csp[0][kk] + csp[1][kk]) + (csp[2][kk] + csp[3][kk]);
    }

    const int base = (blockIdx.x * 4 + wv) * TPW;   // first tile of this wave

    #pragma unroll
    for (int t = 0; t < TPW; ++t) {
        const int tile = base + t;
        const int n0   = tile * 32;

        // ---- A-frags: global fp32 -> bf16 regs (no LDS round trip) ----
        short8 Af[2][4];    // [mf][ks]
        #pragma unroll
        for (int mf = 0; mf < 2; ++mf) {
            const float* rp = xb + (size_t)(n0 + mf * 16 + m16) * NHID + quad * 8;
            #pragma unroll
            for (int ks = 0; ks < 4; ++ks) {
                f32x4 v0 = *(const f32x4*)(rp + ks * 32);
                f32x4 v1 = *(const f32x4*)(rp + ks * 32 + 4);
                u32x4 u;
                u.x = cvt_pk_u32(v0.x, v0.y);
                u.y = cvt_pk_u32(v0.z, v0.w);
                u.z = cvt_pk_u32(v1.x, v1.y);
                u.w = cvt_pk_u32(v1.z, v1.w);
                __builtin_memcpy(&Af[mf][ks], &u, 16);
            }
        }

        f32x4 acc[2][4];
        #pragma unroll
        for (int mf = 0; mf < 2; ++mf)
            #pragma unroll
            for (int nf = 0; nf < 4; ++nf) {
                f32x4 z = {cv[nf], cv[nf], cv[nf], cv[nf]};
                acc[mf][nf] = z;
            }

        #pragma unroll
        for (int ks = 0; ks < 4; ++ks) {
            short8 Bf[4];
            #pragma unroll
            for (int nf = 0; nf < 4; ++nf)
                Bf[nf] = *(const short8*)&WbT[nf * 16 + m16][ks * 32 + quad * 8];
            #pragma unroll
            for (int mf = 0; mf < 2; ++mf)
                #pragma unroll
                for (int nf = 0; nf < 4; ++nf)
                    acc[mf][nf] = __builtin_amdgcn_mfma_f32_16x16x32_bf16(
                        Af[mf][ks], Bf[nf], acc[mf][nf], 0, 0, 0);
        }

        // ---- epilogue: att[n] = b2 + sum_k relu(h[n][k]) * W2[k] ----
        // C layout: row(n-in-tile) = mf*16 + quad*4 + r, col(hidden k) = nf*16+m16
        float att[2][4];
        #pragma unroll
        for (int mf = 0; mf < 2; ++mf)
            #pragma unroll
            for (int r = 0; r < 4; ++r) {
                float s = 0.0f;
                #pragma unroll
                for (int nf = 0; nf < 4; ++nf)
                    s = fmaf(fmaxf(acc[mf][nf][r], 0.0f), w2v[nf], s);
                s += __shfl_xor(s, 1);
                s += __shfl_xor(s, 2);
                s += __shfl_xor(s, 4);
                s += __shfl_xor(s, 8);
                att[mf][r] = s + b2v;
            }

        // ---- exp (no max subtraction) + L reduce ----
        float ev[2][4];
        float L = 0.0f;
        #pragma unroll
        for (int mf = 0; mf < 2; ++mf)
            #pragma unroll
            for (int r = 0; r < 4; ++r) {
                ev[mf][r] = __expf(att[mf][r]);
                L += ev[mf][r];
            }
        L += __shfl_xor(L, 16);
        L += __shfl_xor(L, 32);

        if (m16 == 0) {
            #pragma unroll
            for (int mf = 0; mf < 2; ++mf)
                #pragma unroll
                for (int r = 0; r < 4; ++r)
                    ebuf[wv][mf * 16 + quad * 4 + r] = ev[mf][r];
        }
        // same-wave DS ordering; compiler inserts lgkmcnt wait before reads

        // ---- weighted sum from LIVE A-frags (no global re-read) ----
        // lane (quad,m16) holds x[m16][d], x[m16+16][d] for
        // d = ks*32 + quad*8 + j. Rounds 1-2 fused per ks: only p8[8]
        // survives the loop (R4's po[32]/p16[16] spilled to scratch).
        const float e0 = ebuf[wv][m16];
        const float e1 = ebuf[wv][m16 + 16];
        const bool up1 = (m16 & 1);
        const bool up2 = (m16 & 2);
        float p8[8];
        #pragma unroll
        for (int ks = 0; ks < 4; ++ks) {
            u32x4 a0, a1;
            __builtin_memcpy(&a0, &Af[0][ks], 16);
            __builtin_memcpy(&a1, &Af[1][ks], 16);
            float q[8];
            #pragma unroll
            for (int w = 0; w < 4; ++w) {
                const float x0l = __uint_as_float(a0[w] << 16);
                const float x0h = __uint_as_float(a0[w] & 0xffff0000u);
                const float x1l = __uint_as_float(a1[w] << 16);
                const float x1h = __uint_as_float(a1[w] & 0xffff0000u);
                q[w * 2]     = fmaf(e0, x0l, e1 * x1l);
                q[w * 2 + 1] = fmaf(e0, x0h, e1 * x1h);
            }
            // round 1 (xor 1): local slot pairs (i0, i0|2)
            float r1[4];
            #pragma unroll
            for (int s = 0; s < 4; ++s) {
                const int i0 = ((s >> 1) << 2) | (s & 1);   // 0,1,4,5
                const int i1 = i0 | 2;
                const float send = up1 ? q[i0] : q[i1];
                const float recv = __shfl_xor(send, 1);
                r1[s] = (up1 ? q[i1] : q[i0]) + recv;
            }
            // round 2 (xor 2): pairs (s, s|2) within r1
            #pragma unroll
            for (int s = 0; s < 2; ++s) {
                const float send = up2 ? r1[s] : r1[s | 2];
                const float recv = __shfl_xor(send, 2);
                p8[ks * 2 + s] = (up2 ? r1[s | 2] : r1[s]) + recv;
            }
        }
        // round 3 (xor 4): pairs (i0, i0|2) over p8
        float p4[4];
        {
            const bool up = (m16 & 4);
            #pragma unroll
            for (int s = 0; s < 4; ++s) {
                const int i0 = ((s >> 1) << 2) | (s & 1);   // 0,1,4,5
                const int i1 = i0 | 2;
                const float send = up ? p8[i0] : p8[i1];
                const float recv = __shfl_xor(send, 4);
                p4[s] = (up ? p8[i1] : p8[i0]) + recv;
            }
        }
        // round 4 (xor 8)
        float p2[2];
        {
            const bool up = (m16 & 8);
            #pragma unroll
            for (int s = 0; s < 2; ++s) {
                const float send = up ? p4[s] : p4[s | 2];
                const float recv = __shfl_xor(send, 8);
                p2[s] = (up ? p4[s | 2] : p4[s]) + recv;
            }
        }
        // lane's final slots: d0 = (m16>>2)*32 + quad*8 + (m16&3)*2
        float* p = part + (size_t)(b * NPART + tile) * PART_STRIDE;
        if (lane == 0) p[0] = L;
        const int d0 = (m16 >> 2) * 32 + quad * 8 + (m16 & 3) * 2;
        float2 o2 = make_float2(p2[0], p2[1]);
        *(float2*)(p + O_OFF + d0) = o2;
    }
}

// --------------------------------------------------------------------------
// Kernel C: merge 128 partials per batch -> out[b][d]
// No max pass: S = sum of L_p (block reduce), then a coalesced plain sum
// over partials. No exp, single __syncthreads.
// --------------------------------------------------------------------------
__global__ void finalize(const float* __restrict__ part,
                         float* __restrict__ out) {
    __shared__ float wred[2];

    const int b = blockIdx.x;
    const int d = threadIdx.x;     // 0..127 (= partial index in phase 1)
    const float* pb = part + (size_t)b * NPART * PART_STRIDE;

    // phase 1: S = sum of per-partial L
    float s = pb[(size_t)d * PART_STRIDE];
    s += __shfl_xor(s, 1);
    s += __shfl_xor(s, 2);
    s += __shfl_xor(s, 4);
    s += __shfl_xor(s, 8);
    s += __shfl_xor(s, 16);
    s += __shfl_xor(s, 32);
    if ((d & 63) == 0) wred[d >> 6] = s;
    __syncthreads();
    const float S = wred[0] + wred[1];

    // phase 2: acc over partials, d is the hidden index (coalesced)
    float acc = 0.0f;
    #pragma unroll 8
    for (int p = 0; p < NPART; ++p)
        acc += pb[(size_t)p * PART_STRIDE + O_OFF + d];
    out[b * NHID + d] = acc / S;
}

// --------------------------------------------------------------------------
extern "C" void kernel_launch(void* const* d_in, const int* in_sizes, int n_in,
                              void* d_out, int out_size, void* d_ws, size_t ws_size,
                              hipStream_t stream) {
    const float* inputs = (const float*)d_in[0];
    const int*   index  = (const int*)  d_in[1];
    // d_in[2] = claims (unused by forward)
    const float* W1     = (const float*)d_in[3];
    const float* b1     = (const float*)d_in[4];
    const float* W2     = (const float*)d_in[5];
    const float* b2     = (const float*)d_in[6];
    float* out = (float*)d_out;

    float* part = (float*)d_ws;                 // 128*128*136 floats ~= 8.9 MB

    dim3 gB(NPART / (4 * TPW), BATCH);          // 16 x 128 = 2048 blocks, 4 waves
    att_partial<<<gB, dim3(256), 0, stream>>>(inputs, index, W1, b1, W2, b2, part);

    finalize<<<dim3(BATCH), dim3(NHID), 0, stream>>>(part, out);
}

// Round 6
// 376.383 us; speedup vs baseline: 1.2878x; 1.0838x over previous
//
#include <hip/hip_runtime.h>
#include <math.h>

#define BATCH 128
#define NINS  4096
#define NHID  128
#define KH    64
#define NPART 128                   // 128 tiles of 32 n per batch
#define PART_STRIDE 136             // [0]=L, [8..135]=o[128]; 16B-aligned
#define O_OFF 8
#define TPW 2                       // tiles per wave
#define XP 136                      // row pitch in ushort (128 bf16 + 8 pad)

typedef __attribute__((ext_vector_type(8))) short short8;   // 8 x bf16
typedef __attribute__((ext_vector_type(4))) float f32x4;
typedef __attribute__((ext_vector_type(4))) unsigned int u32x4;

__device__ inline unsigned short f2bf(float f) {
    union { float f; unsigned u; } v; v.f = f;
    return (unsigned short)((v.u + 0x7FFFu + ((v.u >> 16) & 1u)) >> 16);
}

// packed fp32x2 -> bf16x2 as u32 (hardware v_cvt_pk_bf16_f32 on gfx950)
__device__ inline unsigned cvt_pk_u32(float a, float b) {
#if __has_builtin(__builtin_amdgcn_cvt_pk_bf16_f32)
    typedef __attribute__((ext_vector_type(2))) __bf16 bf16x2;
    bf16x2 p = __builtin_amdgcn_cvt_pk_bf16_f32(a, b);
    unsigned u; __builtin_memcpy(&u, &p, 4); return u;
#else
    return (unsigned)f2bf(a) | ((unsigned)f2bf(b) << 16);
#endif
}

// --------------------------------------------------------------------------
// Kernel B: MFMA main pass, direct global->register A-fragments (compiler-
// scheduled). Fused c-compute (R3). No per-tile max subtraction (R3).
// R6: the bf16 tile is WRITTEN THROUGH to LDS during frag conversion
// (Xs[wv][32][XP], 16B ds_write at the 2-way/free column pattern XP=136
// gives), and the weighted sum o[d] = sum_n e_n x[n][d] reads bf16 from
// LDS — eliminating the global re-read (R3: ~20 us of partial L2-miss,
// 8 MB/XCD streaming set vs 4 MB L2) without R4/R5's serial butterfly.
// Af dies right after MFMA (no register-pressure spike; R4 spilled at 62
// live floats). LDS 52.5 KB -> 3 blocks/CU, VGPR slack to 168.
// --------------------------------------------------------------------------
__global__ __launch_bounds__(256, 3)
void att_partial(const float* __restrict__ inputs,
                 const int* __restrict__ index_p,
                 const float* __restrict__ W1,
                 const float* __restrict__ b1,
                 const float* __restrict__ W2,
                 const float* __restrict__ b2_p,
                 float* __restrict__ part) {
    __shared__ unsigned short WbT[KH][XP];       // [out k][hidden d] bf16, 17.4 KB
    __shared__ unsigned short Xs[4][32][XP];     // per-wave bf16 tile, 34.8 KB
    __shared__ float csp[4][KH];                 // c partial sums (d-quarters)
    __shared__ float ebuf[4][32];

    const int tid  = threadIdx.x;
    const int lane = tid & 63;
    const int wv   = tid >> 6;
    const int b    = blockIdx.y;
    const int quad = lane >> 4;
    const int m16  = lane & 15;

    const float* xb = inputs + (size_t)b * NINS * NHID;

    // ---- stage WbT[k][d] = bf16(W1[128+d][k]) (whole block, once) ----
    {
        const int n  = tid >> 2;            // 0..63 (output k)
        const int kb = (tid & 3) * 32;      // 0,32,64,96 (hidden d base)
        const float* wp = W1 + (size_t)(NHID + kb) * KH + n;
        #pragma unroll
        for (int j = 0; j < 32; j += 2) {
            unsigned u = cvt_pk_u32(wp[(size_t)j * KH], wp[(size_t)(j + 1) * KH]);
            *(unsigned*)&WbT[n][kb + j] = u;
        }
    }

    // ---- fused c-compute: csp[q][k] = partial_d own[d]*W1[d][k] ----
    {
        const int kk = lane;                 // 0..63
        const int dq = wv;                   // d-quarter
        const int idx = index_p[0];
        const float* own = xb + (size_t)idx * NHID;
        float ca = (dq == 0) ? b1[kk] : 0.0f;
        #pragma unroll 8
        for (int d = dq * 32; d < dq * 32 + 32; ++d)
            ca = fmaf(own[d], W1[(size_t)d * KH + kk], ca);
        csp[dq][kk] = ca;
    }
    __syncthreads();

    float w2v[4];
    #pragma unroll
    for (int nf = 0; nf < 4; ++nf) w2v[nf] = W2[nf * 16 + m16];
    const float b2v = b2_p[0];
    float cv[4];
    #pragma unroll
    for (int nf = 0; nf < 4; ++nf) {
        const int kk = nf * 16 + m16;
        cv[nf] = (csp[0][kk] + csp[1][kk]) + (csp[2][kk] + csp[3][kk]);
    }

    const int base = (blockIdx.x * 4 + wv) * TPW;   // first tile of this wave

    #pragma unroll
    for (int t = 0; t < TPW; ++t) {
        const int tile = base + t;
        const int n0   = tile * 32;

        // ---- A-frags: global fp32 -> bf16 regs, written through to LDS ----
        short8 Af[2][4];    // [mf][ks]
        #pragma unroll
        for (int mf = 0; mf < 2; ++mf) {
            const float* rp = xb + (size_t)(n0 + mf * 16 + m16) * NHID + quad * 8;
            #pragma unroll
            for (int ks = 0; ks < 4; ++ks) {
                f32x4 v0 = *(const f32x4*)(rp + ks * 32);
                f32x4 v1 = *(const f32x4*)(rp + ks * 32 + 4);
                u32x4 u;
                u.x = cvt_pk_u32(v0.x, v0.y);
                u.y = cvt_pk_u32(v0.z, v0.w);
                u.z = cvt_pk_u32(v1.x, v1.y);
                u.w = cvt_pk_u32(v1.z, v1.w);
                __builtin_memcpy(&Af[mf][ks], &u, 16);
                // write-through: row = mf*16+m16, d = ks*32+quad*8 (16B aligned)
                __builtin_memcpy(&Xs[wv][mf * 16 + m16][ks * 32 + quad * 8], &u, 16);
            }
        }

        f32x4 acc[2][4];
        #pragma unroll
        for (int mf = 0; mf < 2; ++mf)
            #pragma unroll
            for (int nf = 0; nf < 4; ++nf) {
                f32x4 z = {cv[nf], cv[nf], cv[nf], cv[nf]};
                acc[mf][nf] = z;
            }

        #pragma unroll
        for (int ks = 0; ks < 4; ++ks) {
            short8 Bf[4];
            #pragma unroll
            for (int nf = 0; nf < 4; ++nf)
                Bf[nf] = *(const short8*)&WbT[nf * 16 + m16][ks * 32 + quad * 8];
            #pragma unroll
            for (int mf = 0; mf < 2; ++mf)
                #pragma unroll
                for (int nf = 0; nf < 4; ++nf)
                    acc[mf][nf] = __builtin_amdgcn_mfma_f32_16x16x32_bf16(
                        Af[mf][ks], Bf[nf], acc[mf][nf], 0, 0, 0);
        }

        // ---- epilogue: att[n] = b2 + sum_k relu(h[n][k]) * W2[k] ----
        // C layout: row(n-in-tile) = mf*16 + quad*4 + r, col(hidden k) = nf*16+m16
        float att[2][4];
        #pragma unroll
        for (int mf = 0; mf < 2; ++mf)
            #pragma unroll
            for (int r = 0; r < 4; ++r) {
                float s = 0.0f;
                #pragma unroll
                for (int nf = 0; nf < 4; ++nf)
                    s = fmaf(fmaxf(acc[mf][nf][r], 0.0f), w2v[nf], s);
                s += __shfl_xor(s, 1);
                s += __shfl_xor(s, 2);
                s += __shfl_xor(s, 4);
                s += __shfl_xor(s, 8);
                att[mf][r] = s + b2v;
            }

        // ---- exp (no max subtraction) + L reduce ----
        float ev[2][4];
        float L = 0.0f;
        #pragma unroll
        for (int mf = 0; mf < 2; ++mf)
            #pragma unroll
            for (int r = 0; r < 4; ++r) {
                ev[mf][r] = __expf(att[mf][r]);
                L += ev[mf][r];
            }
        L += __shfl_xor(L, 16);
        L += __shfl_xor(L, 32);

        if (m16 == 0) {
            #pragma unroll
            for (int mf = 0; mf < 2; ++mf)
                #pragma unroll
                for (int r = 0; r < 4; ++r)
                    ebuf[wv][mf * 16 + quad * 4 + r] = ev[mf][r];
        }
        // same-wave DS ordering; compiler inserts lgkmcnt wait before reads

        // ---- weighted sum: o[d] = sum_n e_n * x[n][d]  (x bf16, from LDS) ----
        const int G  = lane >> 5;            // n-half (16 each)
        const int db = (lane & 31) * 4;      // d-base (4 values)
        f32x4 e4[4];
        #pragma unroll
        for (int i = 0; i < 4; ++i)
            e4[i] = *(const f32x4*)&ebuf[wv][G * 16 + i * 4];

        f32x4 o = {0.0f, 0.0f, 0.0f, 0.0f};
        #pragma unroll
        for (int jj = 0; jj < 16; ++jj) {
            uint2 u2 = *(const uint2*)&Xs[wv][G * 16 + jj][db];
            f32x4 xv;
            xv.x = __uint_as_float(u2.x << 16);
            xv.y = __uint_as_float(u2.x & 0xffff0000u);
            xv.z = __uint_as_float(u2.y << 16);
            xv.w = __uint_as_float(u2.y & 0xffff0000u);
            o += xv * e4[jj >> 2][jj & 3];
        }
        #pragma unroll
        for (int i = 0; i < 4; ++i) o[i] += __shfl_xor(o[i], 32);

        float* p = part + (size_t)(b * NPART + tile) * PART_STRIDE;
        if (lane == 0) p[0] = L;
        if (lane < 32) *(f32x4*)(p + O_OFF + db) = o;
    }
}

// --------------------------------------------------------------------------
// Kernel C: merge 128 partials per batch -> out[b][d]
// No max pass: S = sum of L_p (block reduce), then a coalesced plain sum
// over partials. No exp, single __syncthreads.
// --------------------------------------------------------------------------
__global__ void finalize(const float* __restrict__ part,
                         float* __restrict__ out) {
    __shared__ float wred[2];

    const int b = blockIdx.x;
    const int d = threadIdx.x;     // 0..127 (= partial index in phase 1)
    const float* pb = part + (size_t)b * NPART * PART_STRIDE;

    // phase 1: S = sum of per-partial L
    float s = pb[(size_t)d * PART_STRIDE];
    s += __shfl_xor(s, 1);
    s += __shfl_xor(s, 2);
    s += __shfl_xor(s, 4);
    s += __shfl_xor(s, 8);
    s += __shfl_xor(s, 16);
    s += __shfl_xor(s, 32);
    if ((d & 63) == 0) wred[d >> 6] = s;
    __syncthreads();
    const float S = wred[0] + wred[1];

    // phase 2: acc over partials, d is the hidden index (coalesced)
    float acc = 0.0f;
    #pragma unroll 8
    for (int p = 0; p < NPART; ++p)
        acc += pb[(size_t)p * PART_STRIDE + O_OFF + d];
    out[b * NHID + d] = acc / S;
}

// --------------------------------------------------------------------------
extern "C" void kernel_launch(void* const* d_in, const int* in_sizes, int n_in,
                              void* d_out, int out_size, void* d_ws, size_t ws_size,
                              hipStream_t stream) {
    const float* inputs = (const float*)d_in[0];
    const int*   index  = (const int*)  d_in[1];
    // d_in[2] = claims (unused by forward)
    const float* W1     = (const float*)d_in[3];
    const float* b1     = (const float*)d_in[4];
    const float* W2     = (const float*)d_in[5];
    const float* b2     = (const float*)d_in[6];
    float* out = (float*)d_out;

    float* part = (float*)d_ws;                 // 128*128*136 floats ~= 8.9 MB

    dim3 gB(NPART / (4 * TPW), BATCH);          // 16 x 128 = 2048 blocks, 4 waves
    att_partial<<<gB, dim3(256), 0, stream>>>(inputs, index, W1, b1, W2, b2, part);

    finalize<<<dim3(BATCH), dim3(NHID), 0, stream>>>(part, out);
}